// Round 1
// 527.915 us; speedup vs baseline: 1.0082x; 1.0082x over previous
//
#include <hip/hip_runtime.h>
#include <math.h>

#define BITS 12
#define NUM_CODES 4096
#define ROWS (4 * 8192)            // b*s positions
#define NATF 0.69314718055994530942f

// The one-hot output is 134M floats with only 32768 ones. Instead of streaming
// 537 MB of zeros from a compute kernel (measured ~3 TB/s for our nontemporal
// row-streamer), zero the whole buffer with hipMemsetAsync — which lowers to
// the runtime's fillBufferAligned, measured on this chip at 6.27 TB/s — and
// scatter-write just the 32768 ones (~2 MB of dirty lines).
//
// scatter: 256-thread blocks, 4 waves; each wave owns one row. Lanes 0..11
// compute the sampled bit via rand <= sigmoid(logit); __ballot bit k == bit k
// of the code index (power-of-two sum is free). Lane 0 stores the single 1.0f.
// fp64 sigmoid rounded to fp32: matches the fp32 numpy reference at rand ~ p
// decision boundaries (absmax 0.0 in earlier rounds) — semantics unchanged.
__global__ __launch_bounds__(256)
void scatter_kernel(const float* __restrict__ logits,
                    const float* __restrict__ rand_unif,
                    float* __restrict__ out)
{
    const int wave = threadIdx.x >> 6;
    const int lane = threadIdx.x & 63;
    const int row  = blockIdx.x * 4 + wave;

    bool pred = false;
    if (lane < BITS) {
        float x = logits[row * BITS + lane];
        float r = rand_unif[row * BITS + lane];
        float p = (float)(1.0 / (1.0 + exp(-(double)x)));
        pred = (r <= p);
    }
    unsigned long long b = __ballot(pred);   // wave-wide on CDNA (64-bit)
    if (lane == 0) {
        const int idx = (int)(b & 0xFFFULL); // lanes 0..11 -> bits 0..11
        out[(size_t)row * NUM_CODES + idx] = 1.0f;
    }
}

// aux_kl_loss = mean over positions of relu(BITS*ln2 - entropy - ln2).
// 32768 positions, one thread each; wave shuffle reduce -> LDS -> one
// atomicAdd per 256-thread block (128 atomics total). Unchanged from the
// passing round (absmax 0.0).
__global__ __launch_bounds__(256)
void loss_kernel(const float* __restrict__ logits, float* __restrict__ loss_out)
{
    int pos = blockIdx.x * blockDim.x + threadIdx.x;
    float contrib = 0.f;
    if (pos < ROWS) {
        const float* lg = logits + pos * BITS;
        float H = 0.f;
        #pragma unroll
        for (int k = 0; k < BITS; ++k) {
            float x  = lg[k];
            float ax = fabsf(x);
            float e  = expf(-ax);
            // binary entropy of sigmoid(x): log1p(e^-|x|) + |x| * sigma(-|x|)
            H += log1pf(e) + ax * (e / (1.f + e));
        }
        float kl     = BITS * NATF - H;
        float hinged = kl - NATF;
        contrib = (hinged > 0.f) ? hinged * (1.f / (float)ROWS) : 0.f;
    }
    #pragma unroll
    for (int off = 32; off > 0; off >>= 1)
        contrib += __shfl_down(contrib, off, 64);

    __shared__ float ws[4];
    int wv = threadIdx.x >> 6;
    if ((threadIdx.x & 63) == 0) ws[wv] = contrib;
    __syncthreads();
    if (threadIdx.x == 0) {
        float s = ws[0] + ws[1] + ws[2] + ws[3];
        atomicAdd(loss_out, s);
    }
}

extern "C" void kernel_launch(void* const* d_in, const int* in_sizes, int n_in,
                              void* d_out, int out_size, void* d_ws, size_t ws_size,
                              hipStream_t stream)
{
    const float* logits    = (const float*)d_in[0];
    const float* rand_unif = (const float*)d_in[1];
    float* out = (float*)d_out;
    float* loss_out = out + (size_t)ROWS * NUM_CODES;  // element 134217728

    // One fast device fill zeroes the entire one-hot region AND the loss
    // scalar (d_out is poisoned with 0xAA each call). This is the runtime's
    // fillBufferAligned path — measured 6.27 TB/s on this chip.
    (void)hipMemsetAsync(d_out, 0,
                         (size_t)ROWS * NUM_CODES * sizeof(float) + sizeof(float),
                         stream);

    loss_kernel<<<ROWS / 256, 256, 0, stream>>>(logits, loss_out);
    scatter_kernel<<<ROWS / 4, 256, 0, stream>>>(logits, rand_unif, out);
}

// Round 2
// 523.233 us; speedup vs baseline: 1.0172x; 1.0089x over previous
//
#include <hip/hip_runtime.h>
#include <math.h>

#define BITS 12
#define NUM_CODES 4096
#define ROWS (4 * 8192)            // b*s positions
#define NATF 0.69314718055994530942f

// Structure (round 2): 2 dispatches instead of 3.
//   1. hipMemsetAsync zeroes the 537 MB one-hot region + the loss scalar.
//      This rides fillBufferAligned, measured 6.2-6.4 TB/s on this chip —
//      the write floor for 537 MB is ~86 us; our round-0 custom streamer
//      measured the same, so memset is kept.
//   2. One fused kernel: all 8192 blocks do the ballot-scatter (one 1.0f per
//      row); blocks 0..127 ALSO run the loss computation with the exact
//      per-thread sequential-k summation + 128-block atomic structure of the
//      previous passing rounds (bit-identical contributions, absmax 0.0).
//
// The 2.147 GB / ~345 us fillBufferAligned in the counters is the harness's
// 0xAA poison — present even in round 0 (which issued only a 4-byte memset) —
// it is inside the timed window and not controllable from here.
__global__ __launch_bounds__(256)
void fused_kernel(const float* __restrict__ logits,
                  const float* __restrict__ rand_unif,
                  float* __restrict__ out,
                  float* __restrict__ loss_out)
{
    const int wave = threadIdx.x >> 6;
    const int lane = threadIdx.x & 63;
    const int row  = blockIdx.x * 4 + wave;

    // ---- scatter: one wave per row, ballot builds the code index ----
    bool pred = false;
    if (lane < BITS) {
        float x = logits[row * BITS + lane];
        float r = rand_unif[row * BITS + lane];
        // fp64 sigmoid rounded to fp32: matches the fp32 numpy reference at
        // rand ~ p decision boundaries (absmax 0.0 across all prior rounds).
        float p = (float)(1.0 / (1.0 + exp(-(double)x)));
        pred = (r <= p);
    }
    unsigned long long b = __ballot(pred);   // wave-wide on CDNA (64-bit)
    if (lane == 0) {
        const int idx = (int)(b & 0xFFFULL); // lanes 0..11 -> bits 0..11
        out[(size_t)row * NUM_CODES + idx] = 1.0f;   // after memset in stream order
    }

    // ---- loss: only blocks 0..127, one position per thread (32768 total).
    // Identical arithmetic + reduction structure to the passing loss_kernel:
    // sequential k-loop per thread, wave shuffle tree, LDS, 1 atomic/block.
    if (blockIdx.x < (ROWS / 256)) {
        const int pos = blockIdx.x * 256 + threadIdx.x;
        const float* lg = logits + pos * BITS;
        float H = 0.f;
        #pragma unroll
        for (int k = 0; k < BITS; ++k) {
            float x  = lg[k];
            float ax = fabsf(x);
            float e  = expf(-ax);
            // binary entropy of sigmoid(x): log1p(e^-|x|) + |x| * sigma(-|x|)
            H += log1pf(e) + ax * (e / (1.f + e));
        }
        float kl     = BITS * NATF - H;
        float hinged = kl - NATF;
        float contrib = (hinged > 0.f) ? hinged * (1.f / (float)ROWS) : 0.f;

        #pragma unroll
        for (int off = 32; off > 0; off >>= 1)
            contrib += __shfl_down(contrib, off, 64);

        __shared__ float ws[4];
        if (lane == 0) ws[wave] = contrib;
        __syncthreads();                      // block-uniform: blockIdx < 128
        if (threadIdx.x == 0) {
            float s = ws[0] + ws[1] + ws[2] + ws[3];
            atomicAdd(loss_out, s);
        }
    }
}

extern "C" void kernel_launch(void* const* d_in, const int* in_sizes, int n_in,
                              void* d_out, int out_size, void* d_ws, size_t ws_size,
                              hipStream_t stream)
{
    const float* logits    = (const float*)d_in[0];
    const float* rand_unif = (const float*)d_in[1];
    float* out = (float*)d_out;
    float* loss_out = out + (size_t)ROWS * NUM_CODES;  // element 134217728

    // Zero the one-hot region AND the poisoned loss scalar in one fill.
    (void)hipMemsetAsync(d_out, 0,
                         (size_t)ROWS * NUM_CODES * sizeof(float) + sizeof(float),
                         stream);

    fused_kernel<<<ROWS / 4, 256, 0, stream>>>(logits, rand_unif, out, loss_out);
}